// Round 5
// baseline (264.493 us; speedup 1.0000x reference)
//
#include <hip/hip_runtime.h>
#include <hip/hip_bf16.h>

// y = (softmax((xWq)(xWk)^T/8) + B) @ (xWv); b=2 s=2048 d=1024 h=16 hd=64
// Split: y = softmax(S)@V * (1/l)  +  B@V
//   conv_x -> wtrans -> qkv_gemm -> vtrans -> fused(attn-role || BV-role) -> add
// fused kernel, 768 blocks x 512 thr:
//   ids 0..511  : attn role (no bias): qtile=128, 8 waves, dbuf K/V LDS,
//                 swapped QK^T, per-lane row-sums, writes Os/l to d_out.
//   ids 512..767: BV role: streaming GEMM Ob = B @ V (bias f32 -> bf16 cvt),
//                 qtile=256, depth-1 bias prefetch, counted vmcnt(8) barrier,
//                 writes Ob to ws Obuf.  Roles co-resident per CU -> bias
//                 stream saturates HBM while attn runs on LDS/MFMA pipes.
// add kernel: out += Obuf.

typedef __attribute__((ext_vector_type(4))) float  f32x4;
typedef __attribute__((ext_vector_type(8))) short  bf16x8;
typedef __attribute__((ext_vector_type(4))) short  s16x4;
typedef __attribute__((ext_vector_type(4))) unsigned u32x4;

__device__ __forceinline__ short f2bf(float f) {
    __hip_bfloat16 h = __float2bfloat16(f);
    return __builtin_bit_cast(short, h);
}

__device__ __forceinline__ unsigned cvt_pk_bf16(float lo, float hi) {
    unsigned w;
    asm("v_cvt_pk_bf16_f32 %0, %1, %2" : "=v"(w) : "v"(lo), "v"(hi));
    return w;
}

__device__ __forceinline__ bf16x8 pack8(f32x4 a, f32x4 b) {
    u32x4 t = (u32x4){cvt_pk_bf16(a[0], a[1]), cvt_pk_bf16(a[2], a[3]),
                      cvt_pk_bf16(b[0], b[1]), cvt_pk_bf16(b[2], b[3])};
    return __builtin_bit_cast(bf16x8, t);
}

__device__ __forceinline__ void gll16(const short* g, short* l) {
    __builtin_amdgcn_global_load_lds(
        (const __attribute__((address_space(1))) void*)g,
        (__attribute__((address_space(3))) void*)l, 16, 0, 0);
}

// ---------------- conv_x ----------------
__global__ void conv_x_kernel(const float* __restrict__ x, short* __restrict__ xb) {
    int idx = blockIdx.x * 256 + threadIdx.x;
    f32x4 v = *reinterpret_cast<const f32x4*>(x + (size_t)idx * 4);
    s16x4 o;
    o[0] = f2bf(v[0]); o[1] = f2bf(v[1]); o[2] = f2bf(v[2]); o[3] = f2bf(v[3]);
    *reinterpret_cast<s16x4*>(xb + (size_t)idx * 4) = o;
}

// ---------------- wtrans ----------------
__global__ void wtrans_kernel(const float* __restrict__ W, short* __restrict__ Wt) {
    __shared__ float tile[64][65];
    int kb = blockIdx.x, nb = blockIdx.y;
    int t = threadIdx.x;
    int c4 = (t & 15) * 4;
    int r0 = t >> 4;
#pragma unroll
    for (int rr = 0; rr < 4; ++rr) {
        int kl = r0 + rr * 16;
        f32x4 v = *reinterpret_cast<const f32x4*>(W + (size_t)(kb * 64 + kl) * 3072 + nb * 64 + c4);
        tile[kl][c4 + 0] = v[0]; tile[kl][c4 + 1] = v[1];
        tile[kl][c4 + 2] = v[2]; tile[kl][c4 + 3] = v[3];
    }
    __syncthreads();
#pragma unroll
    for (int rr = 0; rr < 4; ++rr) {
        int nl = r0 + rr * 16;
        s16x4 o;
#pragma unroll
        for (int i = 0; i < 4; ++i) o[i] = f2bf(tile[c4 + i][nl]);
        *reinterpret_cast<s16x4*>(Wt + (size_t)(nb * 64 + nl) * 1024 + kb * 64 + c4) = o;
    }
}

// ---------------- qkv_gemm (m97 structure) ----------------
__global__ __launch_bounds__(256) void qkv_gemm_kernel(
    const short* __restrict__ xb, const short* __restrict__ Wt,
    const float* __restrict__ bias,
    short* __restrict__ Qo, short* __restrict__ Ko, short* __restrict__ Vo)
{
    __shared__ short As[128 * 64];
    __shared__ short Bs[128 * 64];
    int tid = threadIdx.x;
    int wave = tid >> 6, lane = tid & 63, g = lane >> 4, lr = lane & 15;
    int wr = wave >> 1, wc = wave & 1;
    int bm = blockIdx.x, bn = blockIdx.y;

    f32x4 acc[4][4];
#pragma unroll
    for (int a = 0; a < 4; ++a)
#pragma unroll
        for (int b = 0; b < 4; ++b) acc[a][b] = (f32x4){0.f, 0.f, 0.f, 0.f};

    for (int k0 = 0; k0 < 1024; k0 += 64) {
#pragma unroll
        for (int j = 0; j < 4; ++j) {
            int c = j * 256 + tid;
            int row = c >> 3, cc = c & 7;
            int scc = (cc ^ (row & 7)) * 8;
            gll16(xb + (size_t)(bm * 128 + row) * 1024 + k0 + scc,
                  &As[(j * 256 + wave * 64) * 8]);
            gll16(Wt + (size_t)(bn * 128 + row) * 1024 + k0 + scc,
                  &Bs[(j * 256 + wave * 64) * 8]);
        }
        __syncthreads();

        bf16x8 af[2][4], bfr[2][4];
#pragma unroll
        for (int mt = 0; mt < 4; ++mt) {
            int row = wr * 64 + mt * 16 + lr;
            af[0][mt] = *reinterpret_cast<const bf16x8*>(&As[row * 64 + (((g    ) ^ (lr & 7)) * 8)]);
            af[1][mt] = *reinterpret_cast<const bf16x8*>(&As[row * 64 + (((g + 4) ^ (lr & 7)) * 8)]);
        }
#pragma unroll
        for (int nt = 0; nt < 4; ++nt) {
            int row = wc * 64 + nt * 16 + lr;
            bfr[0][nt] = *reinterpret_cast<const bf16x8*>(&Bs[row * 64 + (((g    ) ^ (lr & 7)) * 8)]);
            bfr[1][nt] = *reinterpret_cast<const bf16x8*>(&Bs[row * 64 + (((g + 4) ^ (lr & 7)) * 8)]);
        }
#pragma unroll
        for (int mt = 0; mt < 4; ++mt)
#pragma unroll
            for (int nt = 0; nt < 4; ++nt) {
                acc[mt][nt] = __builtin_amdgcn_mfma_f32_16x16x32_bf16(af[0][mt], bfr[0][nt], acc[mt][nt], 0, 0, 0);
                acc[mt][nt] = __builtin_amdgcn_mfma_f32_16x16x32_bf16(af[1][mt], bfr[1][nt], acc[mt][nt], 0, 0, 0);
            }
        __syncthreads();
    }

#pragma unroll
    for (int nt = 0; nt < 4; ++nt) {
        int n = bn * 128 + wc * 64 + nt * 16 + lr;
        float bv = bias[n];
        int which = n >> 10;
        int h = (n >> 6) & 15;
        int dd = n & 63;
        short* base = (which == 0) ? Qo : (which == 1) ? Ko : Vo;
#pragma unroll
        for (int mt = 0; mt < 4; ++mt) {
#pragma unroll
            for (int r = 0; r < 4; ++r) {
                int m = bm * 128 + wr * 64 + mt * 16 + g * 4 + r;
                int bb = m >> 11, s = m & 2047;
                float v = acc[mt][nt][r] + bv;
                base[(((size_t)bb * 16 + h) * 2048 + s) * 64 + dd] = f2bf(v);
            }
        }
    }
}

// ---------------- vtrans: V [bh][s][64] -> Vt [bh][64][s] ----------------
__global__ __launch_bounds__(256) void vtrans_kernel(const short* __restrict__ V, short* __restrict__ Vt) {
    __shared__ short t[64][72];
    int st = blockIdx.x, bh = blockIdx.y;
    int tid = threadIdx.x;
#pragma unroll
    for (int j = 0; j < 2; ++j) {
        int c = j * 256 + tid;
        int row = c >> 3, cc = c & 7;
        bf16x8 v = *reinterpret_cast<const bf16x8*>(V + (size_t)((bh * 2048) + st * 64 + row) * 64 + cc * 8);
        *reinterpret_cast<bf16x8*>(&t[row][cc * 8]) = v;
    }
    __syncthreads();
#pragma unroll
    for (int j = 0; j < 2; ++j) {
        int c = j * 256 + tid;
        int d = c >> 3, cs = c & 7;
        bf16x8 o;
#pragma unroll
        for (int i = 0; i < 8; ++i) o[i] = t[cs * 8 + i][d];
        *reinterpret_cast<bf16x8*>(Vt + (size_t)(bh * 64 + d) * 2048 + st * 64 + cs * 8) = o;
    }
}

// ---------------- fused: attn role + BV role ----------------
// ids 0..511: attn. id = (bh&7) + 8*(qt + 16*(bh>>3)); XCD(id%8)==bh%8.
// ids 512..767: BV. j=id-512 = (bh&7) + 8*(qt2 + 8*(bh>>3)); (512+j)%8==bh%8.
__global__ __launch_bounds__(512, 4) void fused_kernel(
    const short* __restrict__ Qw, const short* __restrict__ Kw, const short* __restrict__ Vtw,
    const float* __restrict__ attnB, float* __restrict__ out, float* __restrict__ Obuf)
{
    __shared__ short Ks [2][64 * 64];   // attn: K tiles | BV: Vt tiles
    __shared__ short Vts[2][64 * 64];   // attn: Vt tiles
    __shared__ short Ps [8][16 * 64];   // attn: per-wave P rows

    int id = blockIdx.x;
    int tid = threadIdx.x;
    int wave = tid >> 6, lane = tid & 63, g = lane >> 4, lr = lane & 15;

    if (id < 512) {
        // ================= attn role =================
        int bh3 = id & 7;
        int qt  = (id >> 3) & 15;
        int bh  = ((id >> 7) << 3) | bh3;
        int b = bh >> 4, h = bh & 15;

        const short* Qb = Qw  + (size_t)bh * 2048 * 64;
        const short* Kb = Kw  + (size_t)bh * 2048 * 64;
        const short* Vb = Vtw + (size_t)bh * 64 * 2048;

        int qbase = qt * 128 + wave * 16;

        bf16x8 qf0, qf1;
        {
            const short* qp = Qb + (size_t)(qbase + lr) * 64 + g * 8;
            qf0 = *reinterpret_cast<const bf16x8*>(qp);
            qf1 = *reinterpret_cast<const bf16x8*>(qp + 32);
        }

        f32x4 Os[4];
#pragma unroll
        for (int dt = 0; dt < 4; ++dt) Os[dt] = (f32x4){0.f,0.f,0.f,0.f};
        float lsum = 0.f;

#define STAGE_KV(buf, ktt) do {                                                   \
        int row = tid >> 3, cc = tid & 7;                                         \
        int scc = (cc ^ (row & 7)) * 8;                                           \
        gll16(Kb + (size_t)((ktt) * 64 + row) * 64 + scc,                         \
              &Ks[buf][wave * 512]);                                              \
        gll16(Vb + (size_t)row * 2048 + (ktt) * 64 + scc,                         \
              &Vts[buf][wave * 512]);                                             \
    } while (0)

        STAGE_KV(0, 0);
        asm volatile("s_waitcnt vmcnt(0)" ::: "memory");
        __builtin_amdgcn_s_barrier();
        __builtin_amdgcn_sched_barrier(0);

        for (int kt = 0; kt < 32; ++kt) {
            int cur = kt & 1;
            if (kt < 31) STAGE_KV(cur ^ 1, kt + 1);
            __builtin_amdgcn_sched_barrier(0);

            // swapped QK^T: C[key][q], lane holds q=lr, keys nt*16+4g+r
            f32x4 S[4];
            __builtin_amdgcn_s_setprio(1);
#pragma unroll
            for (int nt = 0; nt < 4; ++nt) {
                int row = nt * 16 + lr;
                bf16x8 kf0 = *reinterpret_cast<const bf16x8*>(&Ks[cur][row * 64 + (((g    ) ^ (lr & 7)) * 8)]);
                bf16x8 kf1 = *reinterpret_cast<const bf16x8*>(&Ks[cur][row * 64 + (((g + 4) ^ (lr & 7)) * 8)]);
                f32x4 s = (f32x4){0.f,0.f,0.f,0.f};
                s = __builtin_amdgcn_mfma_f32_16x16x32_bf16(kf0, qf0, s, 0, 0, 0);
                s = __builtin_amdgcn_mfma_f32_16x16x32_bf16(kf1, qf1, s, 0, 0, 0);
                S[nt] = s;
            }
            __builtin_amdgcn_s_setprio(0);

            // softmax-lite: p = 2^(S * 0.125*log2e)
#pragma unroll
            for (int nt = 0; nt < 4; ++nt)
#pragma unroll
                for (int r = 0; r < 4; ++r) {
                    float p = exp2f(S[nt][r] * 0.1803368801111f);
                    S[nt][r] = p;
                    lsum += p;
                }

            // pack P pairs -> per-wave Ps (A-frag layout, swizzled)
            short* psw = &Ps[wave][lr * 64];
#pragma unroll
            for (int nt = 0; nt < 4; ++nt)
#pragma unroll
                for (int rp = 0; rp < 2; ++rp) {
                    unsigned w = cvt_pk_bf16(S[nt][2 * rp], S[nt][2 * rp + 1]);
                    int kp = 8 * nt + 2 * g + rp;
                    int bi = kp >> 2, off = kp & 3;
                    *reinterpret_cast<unsigned*>(psw + ((bi ^ (lr & 7)) << 3) + off * 2) = w;
                }

            bf16x8 pf0 = *reinterpret_cast<const bf16x8*>(&Ps[wave][lr * 64 + (((g    ) ^ (lr & 7)) * 8)]);
            bf16x8 pf1 = *reinterpret_cast<const bf16x8*>(&Ps[wave][lr * 64 + (((g + 4) ^ (lr & 7)) * 8)]);

            // PV
            __builtin_amdgcn_s_setprio(1);
#pragma unroll
            for (int dt = 0; dt < 4; ++dt) {
                int row = dt * 16 + lr;
                bf16x8 v0 = *reinterpret_cast<const bf16x8*>(&Vts[cur][row * 64 + (((g    ) ^ (lr & 7)) * 8)]);
                bf16x8 v1 = *reinterpret_cast<const bf16x8*>(&Vts[cur][row * 64 + (((g + 4) ^ (lr & 7)) * 8)]);
                Os[dt] = __builtin_amdgcn_mfma_f32_16x16x32_bf16(pf0, v0, Os[dt], 0, 0, 0);
                Os[dt] = __builtin_amdgcn_mfma_f32_16x16x32_bf16(pf1, v1, Os[dt], 0, 0, 0);
            }
            __builtin_amdgcn_s_setprio(0);

            if (kt < 31) {
                asm volatile("s_waitcnt vmcnt(0)" ::: "memory");
                __builtin_amdgcn_s_barrier();
                __builtin_amdgcn_sched_barrier(0);
            }
        }
#undef STAGE_KV

        float l = lsum;
        l += __shfl_xor(l, 16);
        l += __shfl_xor(l, 32);
        float inv = 1.0f / l;
#pragma unroll
        for (int r = 0; r < 4; ++r) {
            float invr = __shfl(inv, g * 4 + r);
            int q = qbase + g * 4 + r;
#pragma unroll
            for (int dt = 0; dt < 4; ++dt) {
                int dcol = dt * 16 + lr;
                out[((size_t)(b * 2048 + q) * 16 + h) * 64 + dcol] = Os[dt][r] * invr;
            }
        }
    } else {
        // ================= BV role: Ob = B @ V =================
        int j = id - 512;
        int bh = ((j >> 6) << 3) | (j & 7);
        int qt2 = (j >> 3) & 7;
        int b = bh >> 4, h = bh & 15;
        int qb = qt2 * 256;

        const float* Bp = attnB + (size_t)bh * 2048 * 2048;
        const short* Vb = Vtw + (size_t)bh * 64 * 2048;
        const float* br0 = Bp + (size_t)(qb + wave * 32 + lr) * 2048 + g * 8;   // mt=0 rows
        const float* br1 = br0 + (size_t)16 * 2048;                              // mt=1 rows

        f32x4 acc[2][4];
#pragma unroll
        for (int mt = 0; mt < 2; ++mt)
#pragma unroll
            for (int nt = 0; nt < 4; ++nt) acc[mt][nt] = (f32x4){0.f,0.f,0.f,0.f};

#define STAGE_V(buf, ktt) do {                                                    \
        int row = tid >> 3, cc = tid & 7;                                         \
        int scc = (cc ^ (row & 7)) * 8;                                           \
        gll16(Vb + (size_t)row * 2048 + (ktt) * 64 + scc,                         \
              &Ks[buf][wave * 512]);                                              \
    } while (0)

        f32x4 b00, b01, b02, b03, b10, b11, b12, b13;   // prefetched bias frags
        STAGE_V(0, 0);
        __builtin_amdgcn_sched_barrier(0);
        b00 = __builtin_nontemporal_load(reinterpret_cast<const f32x4*>(br0));
        b01 = __builtin_nontemporal_load(reinterpret_cast<const f32x4*>(br0 + 4));
        b02 = __builtin_nontemporal_load(reinterpret_cast<const f32x4*>(br0 + 32));
        b03 = __builtin_nontemporal_load(reinterpret_cast<const f32x4*>(br0 + 36));
        b10 = __builtin_nontemporal_load(reinterpret_cast<const f32x4*>(br1));
        b11 = __builtin_nontemporal_load(reinterpret_cast<const f32x4*>(br1 + 4));
        b12 = __builtin_nontemporal_load(reinterpret_cast<const f32x4*>(br1 + 32));
        b13 = __builtin_nontemporal_load(reinterpret_cast<const f32x4*>(br1 + 36));
        asm volatile("s_waitcnt vmcnt(8)" ::: "memory");
        __builtin_amdgcn_s_barrier();
        __builtin_amdgcn_sched_barrier(0);

        for (int kt = 0; kt < 32; ++kt) {
            int cur = kt & 1;

            bf16x8 a00 = pack8(b00, b01);   // mt0, k 0..31
            bf16x8 a01 = pack8(b02, b03);   // mt0, k 32..63
            bf16x8 a10 = pack8(b10, b11);   // mt1, k 0..31
            bf16x8 a11 = pack8(b12, b13);   // mt1, k 32..63

            if (kt < 31) {
                STAGE_V(cur ^ 1, kt + 1);
                __builtin_amdgcn_sched_barrier(0);
                const float* p0 = br0 + (kt + 1) * 64;
                const float* p1 = br1 + (kt + 1) * 64;
                b00 = __builtin_nontemporal_load(reinterpret_cast<const f32x4*>(p0));
                b01 = __builtin_nontemporal_load(reinterpret_cast<const f32x4*>(p0 + 4));
                b02 = __builtin_nontemporal_load(reinterpret_cast<const f32x4*>(p0 + 32));
                b03 = __builtin_nontemporal_load(reinterpret_cast<const f32x4*>(p0 + 36));
                b10 = __builtin_nontemporal_load(reinterpret_cast<const f32x4*>(p1));
                b11 = __builtin_nontemporal_load(reinterpret_cast<const f32x4*>(p1 + 4));
                b12 = __builtin_nontemporal_load(reinterpret_cast<const f32x4*>(p1 + 32));
                b13 = __builtin_nontemporal_load(reinterpret_cast<const f32x4*>(p1 + 36));
            }

            __builtin_amdgcn_s_setprio(1);
#pragma unroll
            for (int nt = 0; nt < 4; ++nt) {
                int row = nt * 16 + lr;
                bf16x8 v0 = *reinterpret_cast<const bf16x8*>(&Ks[cur][row * 64 + (((g    ) ^ (lr & 7)) * 8)]);
                bf16x8 v1 = *reinterpret_cast<const bf16x8*>(&Ks[cur][row * 64 + (((g + 4) ^ (lr & 7)) * 8)]);
                acc[0][nt] = __builtin_amdgcn_mfma_f32_16x16x32_bf16(a00, v0, acc[0][nt], 0, 0, 0);
                acc[0][nt] = __builtin_amdgcn_mfma_f32_16x16x32_bf16(a01, v1, acc[0][nt], 0, 0, 0);
                acc[1][nt] = __builtin_amdgcn_mfma_f32_16x16x32_bf16(a10, v0, acc[1][nt], 0, 0, 0);
                acc[1][nt] = __builtin_amdgcn_mfma_f32_16x16x32_bf16(a11, v1, acc[1][nt], 0, 0, 0);
            }
            __builtin_amdgcn_s_setprio(0);

            if (kt < 31) {
                asm volatile("s_waitcnt vmcnt(8)" ::: "memory");  // stage done; 8 bias in flight
                __builtin_amdgcn_s_barrier();
                __builtin_amdgcn_sched_barrier(0);
            }
        }
#undef STAGE_V

#pragma unroll
        for (int mt = 0; mt < 2; ++mt)
#pragma unroll
            for (int nt = 0; nt < 4; ++nt)
#pragma unroll
                for (int r = 0; r < 4; ++r) {
                    int q = qb + wave * 32 + mt * 16 + g * 4 + r;
                    int d = nt * 16 + lr;
                    Obuf[((size_t)(b * 2048 + q) * 16 + h) * 64 + d] = acc[mt][nt][r];
                }
    }
}

// ---------------- add: out += Obuf ----------------
__global__ void add_kernel(float* __restrict__ out, const float* __restrict__ Obuf) {
    int idx = blockIdx.x * 256 + threadIdx.x;
    f32x4 a = *reinterpret_cast<const f32x4*>(out + (size_t)idx * 4);
    f32x4 c = *reinterpret_cast<const f32x4*>(Obuf + (size_t)idx * 4);
    a[0] += c[0]; a[1] += c[1]; a[2] += c[2]; a[3] += c[3];
    *reinterpret_cast<f32x4*>(out + (size_t)idx * 4) = a;
}

extern "C" void kernel_launch(void* const* d_in, const int* in_sizes, int n_in,
                              void* d_out, int out_size, void* d_ws, size_t ws_size,
                              hipStream_t stream) {
    const float* x     = (const float*)d_in[0];
    const float* attnB = (const float*)d_in[1];
    const float* W     = (const float*)d_in[2];
    const float* bias  = (const float*)d_in[3];
    float* out = (float*)d_out;

    short* ws = (short*)d_ws;
    short* xb = ws;                // 4,194,304 shorts
    short* Wt = xb + 4194304;      // 3,145,728
    short* Q  = Wt + 3145728;      // 4,194,304
    short* K  = Q  + 4194304;      // 4,194,304
    short* V  = K  + 4194304;      // 4,194,304
    short* Vt = V  + 4194304;      // 4,194,304
    float* Obuf = (float*)(Vt + 4194304);   // 4,194,304 floats (16 MB); ~64 MB total

    conv_x_kernel<<<4096, 256, 0, stream>>>(x, xb);
    wtrans_kernel<<<dim3(16, 48), 256, 0, stream>>>(W, Wt);
    qkv_gemm_kernel<<<dim3(32, 24), 256, 0, stream>>>(xb, Wt, bias, Q, K, V);
    vtrans_kernel<<<dim3(32, 32), 256, 0, stream>>>(V, Vt);
    fused_kernel<<<768, 512, 0, stream>>>(Q, K, Vt, attnB, out, Obuf);
    add_kernel<<<4096, 256, 0, stream>>>(out, Obuf);
}

// Round 6
// 235.997 us; speedup vs baseline: 1.1207x; 1.1207x over previous
//
#include <hip/hip_runtime.h>
#include <hip/hip_bf16.h>

// y = (softmax((xWq)(xWk)^T/8) + B) @ (xWv); b=2 s=2048 d=1024 h=16 hd=64
// conv_x -> wtrans -> qkv_gemm (m97-style) -> vtrans -> attn
// attn (this round): KVBLK=128 (16 iters), two 64-key sub-phases per iter,
//   8 bias f32x4 prefetched one FULL iter ahead (2x cover, 2x in-flight vs R4),
//   counted vmcnt(8)+raw s_barrier, swapped QK^T, cvt_pk packing, XCD-clustered
//   block mapping, LDS 80KB -> 2 blocks/CU.

typedef __attribute__((ext_vector_type(4))) float  f32x4;
typedef __attribute__((ext_vector_type(8))) short  bf16x8;
typedef __attribute__((ext_vector_type(4))) short  s16x4;
typedef __attribute__((ext_vector_type(4))) unsigned u32x4;

__device__ __forceinline__ short f2bf(float f) {
    __hip_bfloat16 h = __float2bfloat16(f);
    return __builtin_bit_cast(short, h);
}

__device__ __forceinline__ unsigned cvt_pk_bf16(float lo, float hi) {
    unsigned w;
    asm("v_cvt_pk_bf16_f32 %0, %1, %2" : "=v"(w) : "v"(lo), "v"(hi));
    return w;
}

__device__ __forceinline__ bf16x8 pack8(f32x4 a, f32x4 b) {
    u32x4 t = (u32x4){cvt_pk_bf16(a[0], a[1]), cvt_pk_bf16(a[2], a[3]),
                      cvt_pk_bf16(b[0], b[1]), cvt_pk_bf16(b[2], b[3])};
    return __builtin_bit_cast(bf16x8, t);
}

__device__ __forceinline__ void gll16(const short* g, short* l) {
    __builtin_amdgcn_global_load_lds(
        (const __attribute__((address_space(1))) void*)g,
        (__attribute__((address_space(3))) void*)l, 16, 0, 0);
}

// ---------------- conv_x ----------------
__global__ void conv_x_kernel(const float* __restrict__ x, short* __restrict__ xb) {
    int idx = blockIdx.x * 256 + threadIdx.x;
    f32x4 v = *reinterpret_cast<const f32x4*>(x + (size_t)idx * 4);
    s16x4 o;
    o[0] = f2bf(v[0]); o[1] = f2bf(v[1]); o[2] = f2bf(v[2]); o[3] = f2bf(v[3]);
    *reinterpret_cast<s16x4*>(xb + (size_t)idx * 4) = o;
}

// ---------------- wtrans ----------------
__global__ void wtrans_kernel(const float* __restrict__ W, short* __restrict__ Wt) {
    __shared__ float tile[64][65];
    int kb = blockIdx.x, nb = blockIdx.y;
    int t = threadIdx.x;
    int c4 = (t & 15) * 4;
    int r0 = t >> 4;
#pragma unroll
    for (int rr = 0; rr < 4; ++rr) {
        int kl = r0 + rr * 16;
        f32x4 v = *reinterpret_cast<const f32x4*>(W + (size_t)(kb * 64 + kl) * 3072 + nb * 64 + c4);
        tile[kl][c4 + 0] = v[0]; tile[kl][c4 + 1] = v[1];
        tile[kl][c4 + 2] = v[2]; tile[kl][c4 + 3] = v[3];
    }
    __syncthreads();
#pragma unroll
    for (int rr = 0; rr < 4; ++rr) {
        int nl = r0 + rr * 16;
        s16x4 o;
#pragma unroll
        for (int i = 0; i < 4; ++i) o[i] = f2bf(tile[c4 + i][nl]);
        *reinterpret_cast<s16x4*>(Wt + (size_t)(nb * 64 + nl) * 1024 + kb * 64 + c4) = o;
    }
}

// ---------------- qkv_gemm (m97 structure) ----------------
__global__ __launch_bounds__(256) void qkv_gemm_kernel(
    const short* __restrict__ xb, const short* __restrict__ Wt,
    const float* __restrict__ bias,
    short* __restrict__ Qo, short* __restrict__ Ko, short* __restrict__ Vo)
{
    __shared__ short As[128 * 64];
    __shared__ short Bs[128 * 64];
    int tid = threadIdx.x;
    int wave = tid >> 6, lane = tid & 63, g = lane >> 4, lr = lane & 15;
    int wr = wave >> 1, wc = wave & 1;
    int bm = blockIdx.x, bn = blockIdx.y;

    f32x4 acc[4][4];
#pragma unroll
    for (int a = 0; a < 4; ++a)
#pragma unroll
        for (int b = 0; b < 4; ++b) acc[a][b] = (f32x4){0.f, 0.f, 0.f, 0.f};

    for (int k0 = 0; k0 < 1024; k0 += 64) {
#pragma unroll
        for (int j = 0; j < 4; ++j) {
            int c = j * 256 + tid;
            int row = c >> 3, cc = c & 7;
            int scc = (cc ^ (row & 7)) * 8;
            gll16(xb + (size_t)(bm * 128 + row) * 1024 + k0 + scc,
                  &As[(j * 256 + wave * 64) * 8]);
            gll16(Wt + (size_t)(bn * 128 + row) * 1024 + k0 + scc,
                  &Bs[(j * 256 + wave * 64) * 8]);
        }
        __syncthreads();

        bf16x8 af[2][4], bfr[2][4];
#pragma unroll
        for (int mt = 0; mt < 4; ++mt) {
            int row = wr * 64 + mt * 16 + lr;
            af[0][mt] = *reinterpret_cast<const bf16x8*>(&As[row * 64 + (((g    ) ^ (lr & 7)) * 8)]);
            af[1][mt] = *reinterpret_cast<const bf16x8*>(&As[row * 64 + (((g + 4) ^ (lr & 7)) * 8)]);
        }
#pragma unroll
        for (int nt = 0; nt < 4; ++nt) {
            int row = wc * 64 + nt * 16 + lr;
            bfr[0][nt] = *reinterpret_cast<const bf16x8*>(&Bs[row * 64 + (((g    ) ^ (lr & 7)) * 8)]);
            bfr[1][nt] = *reinterpret_cast<const bf16x8*>(&Bs[row * 64 + (((g + 4) ^ (lr & 7)) * 8)]);
        }
#pragma unroll
        for (int mt = 0; mt < 4; ++mt)
#pragma unroll
            for (int nt = 0; nt < 4; ++nt) {
                acc[mt][nt] = __builtin_amdgcn_mfma_f32_16x16x32_bf16(af[0][mt], bfr[0][nt], acc[mt][nt], 0, 0, 0);
                acc[mt][nt] = __builtin_amdgcn_mfma_f32_16x16x32_bf16(af[1][mt], bfr[1][nt], acc[mt][nt], 0, 0, 0);
            }
        __syncthreads();
    }

#pragma unroll
    for (int nt = 0; nt < 4; ++nt) {
        int n = bn * 128 + wc * 64 + nt * 16 + lr;
        float bv = bias[n];
        int which = n >> 10;
        int h = (n >> 6) & 15;
        int dd = n & 63;
        short* base = (which == 0) ? Qo : (which == 1) ? Ko : Vo;
#pragma unroll
        for (int mt = 0; mt < 4; ++mt) {
#pragma unroll
            for (int r = 0; r < 4; ++r) {
                int m = bm * 128 + wr * 64 + mt * 16 + g * 4 + r;
                int bb = m >> 11, s = m & 2047;
                float v = acc[mt][nt][r] + bv;
                base[(((size_t)bb * 16 + h) * 2048 + s) * 64 + dd] = f2bf(v);
            }
        }
    }
}

// ---------------- vtrans: V [bh][s][64] -> Vt [bh][64][s] ----------------
__global__ __launch_bounds__(256) void vtrans_kernel(const short* __restrict__ V, short* __restrict__ Vt) {
    __shared__ short t[64][72];
    int st = blockIdx.x, bh = blockIdx.y;
    int tid = threadIdx.x;
#pragma unroll
    for (int j = 0; j < 2; ++j) {
        int c = j * 256 + tid;
        int row = c >> 3, cc = c & 7;
        bf16x8 v = *reinterpret_cast<const bf16x8*>(V + (size_t)((bh * 2048) + st * 64 + row) * 64 + cc * 8);
        *reinterpret_cast<bf16x8*>(&t[row][cc * 8]) = v;
    }
    __syncthreads();
#pragma unroll
    for (int j = 0; j < 2; ++j) {
        int c = j * 256 + tid;
        int d = c >> 3, cs = c & 7;
        bf16x8 o;
#pragma unroll
        for (int i = 0; i < 8; ++i) o[i] = t[cs * 8 + i][d];
        *reinterpret_cast<bf16x8*>(Vt + (size_t)(bh * 64 + d) * 2048 + st * 64 + cs * 8) = o;
    }
}

// ---------------- attn ----------------
// grid 512; id = (bh&7) + 8*(qt + 16*(bh>>3)) -> XCD(id%8)==bh%8.
// 512 threads = 8 waves x 16 q-rows (qtile 128), KVBLK=128, dbuf LDS.
__global__ __launch_bounds__(512, 4) void attn_kernel(
    const short* __restrict__ Qw, const short* __restrict__ Kw, const short* __restrict__ Vtw,
    const float* __restrict__ attnB, float* __restrict__ out)
{
    __shared__ short Ks [2][128 * 64];   // [key][d], source-swizzled chunks (32 KB)
    __shared__ short Vts[2][64 * 128];   // [d][key], source-swizzled chunks (32 KB)
    __shared__ short Ps [8][16 * 64];    // per-wave P rows (16 KB)

    int id = blockIdx.x;
    int bh3 = id & 7;
    int qt  = (id >> 3) & 15;
    int bh  = ((id >> 7) << 3) | bh3;
    int b = bh >> 4, h = bh & 15;
    int tid = threadIdx.x;
    int wave = tid >> 6, lane = tid & 63, g = lane >> 4, lr = lane & 15;

    const short* Qb = Qw  + (size_t)bh * 2048 * 64;
    const short* Kb = Kw  + (size_t)bh * 2048 * 64;
    const short* Vb = Vtw + (size_t)bh * 64 * 2048;
    const float* Bp = attnB + (size_t)bh * 2048 * 2048;

    int qbase = qt * 128 + wave * 16;

    bf16x8 qf0, qf1;
    {
        const short* qp = Qb + (size_t)(qbase + lr) * 64 + g * 8;
        qf0 = *reinterpret_cast<const bf16x8*>(qp);
        qf1 = *reinterpret_cast<const bf16x8*>(qp + 32);
    }
    const float* brow = Bp + (size_t)(qbase + lr) * 2048 + g * 8;

    f32x4 Os[4], Ob[4];
#pragma unroll
    for (int dt = 0; dt < 4; ++dt) { Os[dt] = (f32x4){0.f,0.f,0.f,0.f}; Ob[dt] = (f32x4){0.f,0.f,0.f,0.f}; }
    float lsum = 0.f;

    // stage 128-key tile: K 1024 chunks + Vt 1024 chunks; 2 each per thread
#define STAGE_KV(buf, ktt) do {                                                   \
    _Pragma("unroll")                                                             \
    for (int j = 0; j < 2; ++j) {                                                 \
        int c = j * 512 + tid;                                                    \
        int krow = c >> 3, kcc = c & 7;                                           \
        gll16(Kb + (size_t)((ktt) * 128 + krow) * 64 + ((kcc ^ (krow & 7)) * 8),  \
              &Ks[buf][(j * 512 + wave * 64) * 8]);                               \
        int vrow = c >> 4, vcc = c & 15;                                          \
        int vscc = ((vcc & 8) | ((vcc & 7) ^ (vrow & 7))) * 8;                    \
        gll16(Vb + (size_t)vrow * 2048 + (ktt) * 128 + vscc,                      \
              &Vts[buf][(j * 512 + wave * 64) * 8]);                              \
    }                                                                             \
} while (0)

    // prologue: stage tile 0, prefetch bias tile 0 (8x f32x4)
    f32x4 b0, b1, b2, b3, b4, b5, b6, b7;
    STAGE_KV(0, 0);
    __builtin_amdgcn_sched_barrier(0);
    b0 = __builtin_nontemporal_load(reinterpret_cast<const f32x4*>(brow));
    b1 = __builtin_nontemporal_load(reinterpret_cast<const f32x4*>(brow + 4));
    b2 = __builtin_nontemporal_load(reinterpret_cast<const f32x4*>(brow + 32));
    b3 = __builtin_nontemporal_load(reinterpret_cast<const f32x4*>(brow + 36));
    b4 = __builtin_nontemporal_load(reinterpret_cast<const f32x4*>(brow + 64));
    b5 = __builtin_nontemporal_load(reinterpret_cast<const f32x4*>(brow + 68));
    b6 = __builtin_nontemporal_load(reinterpret_cast<const f32x4*>(brow + 96));
    b7 = __builtin_nontemporal_load(reinterpret_cast<const f32x4*>(brow + 100));
    asm volatile("s_waitcnt vmcnt(8)" ::: "memory");   // stage done; 8 bias in flight
    __builtin_amdgcn_s_barrier();
    __builtin_amdgcn_sched_barrier(0);

    for (int kt = 0; kt < 16; ++kt) {
        int cur = kt & 1;

        // consume bias(kt) prefetched one full iter ago
        bf16x8 bbf0 = pack8(b0, b1);   // half0, k 0..31
        bf16x8 bbf1 = pack8(b2, b3);   // half0, k 32..63
        bf16x8 bbf2 = pack8(b4, b5);   // half1, k 0..31
        bf16x8 bbf3 = pack8(b6, b7);   // half1, k 32..63

        // stage K/V(kt+1), then prefetch bias(kt+1) (stays in flight 1 iter)
        if (kt < 15) {
            STAGE_KV(cur ^ 1, kt + 1);
            __builtin_amdgcn_sched_barrier(0);
            const float* bp = brow + (size_t)(kt + 1) * 128;
            b0 = __builtin_nontemporal_load(reinterpret_cast<const f32x4*>(bp));
            b1 = __builtin_nontemporal_load(reinterpret_cast<const f32x4*>(bp + 4));
            b2 = __builtin_nontemporal_load(reinterpret_cast<const f32x4*>(bp + 32));
            b3 = __builtin_nontemporal_load(reinterpret_cast<const f32x4*>(bp + 36));
            b4 = __builtin_nontemporal_load(reinterpret_cast<const f32x4*>(bp + 64));
            b5 = __builtin_nontemporal_load(reinterpret_cast<const f32x4*>(bp + 68));
            b6 = __builtin_nontemporal_load(reinterpret_cast<const f32x4*>(bp + 96));
            b7 = __builtin_nontemporal_load(reinterpret_cast<const f32x4*>(bp + 100));
            __builtin_amdgcn_sched_barrier(0);
        }

#pragma unroll
        for (int hh = 0; hh < 2; ++hh) {
            // ---- swapped QK^T over keys hh*64..hh*64+63 ----
            f32x4 S[4];
            __builtin_amdgcn_s_setprio(1);
#pragma unroll
            for (int nt = 0; nt < 4; ++nt) {
                int row = hh * 64 + nt * 16 + lr;
                bf16x8 kf0 = *reinterpret_cast<const bf16x8*>(&Ks[cur][row * 64 + (((g    ) ^ (lr & 7)) * 8)]);
                bf16x8 kf1 = *reinterpret_cast<const bf16x8*>(&Ks[cur][row * 64 + (((g + 4) ^ (lr & 7)) * 8)]);
                f32x4 s = (f32x4){0.f,0.f,0.f,0.f};
                s = __builtin_amdgcn_mfma_f32_16x16x32_bf16(kf0, qf0, s, 0, 0, 0);
                s = __builtin_amdgcn_mfma_f32_16x16x32_bf16(kf1, qf1, s, 0, 0, 0);
                S[nt] = s;
            }
            __builtin_amdgcn_s_setprio(0);

            // ---- softmax-lite: p = 2^(S * 0.125*log2e) ----
#pragma unroll
            for (int nt = 0; nt < 4; ++nt)
#pragma unroll
                for (int r = 0; r < 4; ++r) {
                    float p = exp2f(S[nt][r] * 0.1803368801111f);
                    S[nt][r] = p;
                    lsum += p;
                }

            // ---- pack P pairs -> per-wave Ps (A-frag layout, swizzled) ----
            short* psw = &Ps[wave][lr * 64];
#pragma unroll
            for (int nt = 0; nt < 4; ++nt)
#pragma unroll
                for (int rp = 0; rp < 2; ++rp) {
                    unsigned w = cvt_pk_bf16(S[nt][2 * rp], S[nt][2 * rp + 1]);
                    int kp = 8 * nt + 2 * g + rp;
                    int bi = kp >> 2, off = kp & 3;
                    *reinterpret_cast<unsigned*>(psw + ((bi ^ (lr & 7)) << 3) + off * 2) = w;
                }

            bf16x8 pf0 = *reinterpret_cast<const bf16x8*>(&Ps[wave][lr * 64 + (((g    ) ^ (lr & 7)) * 8)]);
            bf16x8 pf1 = *reinterpret_cast<const bf16x8*>(&Ps[wave][lr * 64 + (((g + 4) ^ (lr & 7)) * 8)]);
            bf16x8 ba0 = hh ? bbf2 : bbf0;
            bf16x8 ba1 = hh ? bbf3 : bbf1;

            // ---- PV + BV over this key half ----
            __builtin_amdgcn_s_setprio(1);
#pragma unroll
            for (int dt = 0; dt < 4; ++dt) {
                int row = dt * 16 + lr;
                bf16x8 v0 = *reinterpret_cast<const bf16x8*>(&Vts[cur][row * 128 + hh * 64 + (((g    ) ^ (lr & 7)) * 8)]);
                bf16x8 v1 = *reinterpret_cast<const bf16x8*>(&Vts[cur][row * 128 + hh * 64 + (((g + 4) ^ (lr & 7)) * 8)]);
                Os[dt] = __builtin_amdgcn_mfma_f32_16x16x32_bf16(pf0, v0, Os[dt], 0, 0, 0);
                Os[dt] = __builtin_amdgcn_mfma_f32_16x16x32_bf16(pf1, v1, Os[dt], 0, 0, 0);
                Ob[dt] = __builtin_amdgcn_mfma_f32_16x16x32_bf16(ba0, v0, Ob[dt], 0, 0, 0);
                Ob[dt] = __builtin_amdgcn_mfma_f32_16x16x32_bf16(ba1, v1, Ob[dt], 0, 0, 0);
            }
            __builtin_amdgcn_s_setprio(0);
        }

        if (kt < 15) {
            // stage(kt+1) done; 8 bias loads stay in flight across barrier
            asm volatile("s_waitcnt vmcnt(8)" ::: "memory");
            __builtin_amdgcn_s_barrier();
            __builtin_amdgcn_sched_barrier(0);
        }
    }
#undef STAGE_KV

    // ---- epilogue: reduce row sums across the 4 lane-groups ----
    float l = lsum;
    l += __shfl_xor(l, 16);
    l += __shfl_xor(l, 32);
    float inv = 1.0f / l;          // lane holds inv for q = lr
#pragma unroll
    for (int r = 0; r < 4; ++r) {
        float invr = __shfl(inv, g * 4 + r);   // inv for q = 4g + r
        int q = qbase + g * 4 + r;
#pragma unroll
        for (int dt = 0; dt < 4; ++dt) {
            int dcol = dt * 16 + lr;
            float v = Os[dt][r] * invr + Ob[dt][r];
            __builtin_nontemporal_store(v, &out[((size_t)(b * 2048 + q) * 16 + h) * 64 + dcol]);
        }
    }
}

extern "C" void kernel_launch(void* const* d_in, const int* in_sizes, int n_in,
                              void* d_out, int out_size, void* d_ws, size_t ws_size,
                              hipStream_t stream) {
    const float* x     = (const float*)d_in[0];
    const float* attnB = (const float*)d_in[1];
    const float* W     = (const float*)d_in[2];
    const float* bias  = (const float*)d_in[3];
    float* out = (float*)d_out;

    short* ws = (short*)d_ws;
    short* xb = ws;                // 4,194,304 shorts
    short* Wt = xb + 4194304;      // 3,145,728
    short* Q  = Wt + 3145728;      // 4,194,304
    short* K  = Q  + 4194304;      // 4,194,304
    short* V  = K  + 4194304;      // 4,194,304
    short* Vt = V  + 4194304;      // 4,194,304

    conv_x_kernel<<<4096, 256, 0, stream>>>(x, xb);
    wtrans_kernel<<<dim3(16, 48), 256, 0, stream>>>(W, Wt);
    qkv_gemm_kernel<<<dim3(32, 24), 256, 0, stream>>>(xb, Wt, bias, Q, K, V);
    vtrans_kernel<<<dim3(32, 32), 256, 0, stream>>>(V, Vt);
    attn_kernel<<<512, 512, 0, stream>>>(Q, K, Vt, attnB, out);
}

// Round 7
// 208.081 us; speedup vs baseline: 1.2711x; 1.1342x over previous
//
#include <hip/hip_runtime.h>
#include <hip/hip_bf16.h>

// y = (softmax((xWq)(xWk)^T/8) + B) @ (xWv); b=2 s=2048 d=1024 h=16 hd=64
// conv_x -> wtrans -> qkv_gemm (m97-style, V written pre-transposed) -> attn
// attn: R4 structure (KVBLK=64, 48KB LDS, 8 waves x 16 q-rows, XCD-clustered)
//   + TWO-deep bias prefetch (2 rotating reg sets, manual 2x unroll),
//   FIFO order per iter: STAGE(kt+1) then bias(kt+2); vmcnt(4) drains
//   {bias(kt+1), stage(kt+1)}, leaves bias(kt+2) in flight across barrier.

typedef __attribute__((ext_vector_type(4))) float  f32x4;
typedef __attribute__((ext_vector_type(8))) short  bf16x8;
typedef __attribute__((ext_vector_type(4))) short  s16x4;
typedef __attribute__((ext_vector_type(4))) unsigned u32x4;

__device__ __forceinline__ short f2bf(float f) {
    __hip_bfloat16 h = __float2bfloat16(f);
    return __builtin_bit_cast(short, h);
}

__device__ __forceinline__ unsigned cvt_pk_bf16(float lo, float hi) {
    unsigned w;
    asm("v_cvt_pk_bf16_f32 %0, %1, %2" : "=v"(w) : "v"(lo), "v"(hi));
    return w;
}

__device__ __forceinline__ bf16x8 pack8(f32x4 a, f32x4 b) {
    u32x4 t = (u32x4){cvt_pk_bf16(a[0], a[1]), cvt_pk_bf16(a[2], a[3]),
                      cvt_pk_bf16(b[0], b[1]), cvt_pk_bf16(b[2], b[3])};
    return __builtin_bit_cast(bf16x8, t);
}

__device__ __forceinline__ void gll16(const short* g, short* l) {
    __builtin_amdgcn_global_load_lds(
        (const __attribute__((address_space(1))) void*)g,
        (__attribute__((address_space(3))) void*)l, 16, 0, 0);
}

// ---------------- conv_x ----------------
__global__ void conv_x_kernel(const float* __restrict__ x, short* __restrict__ xb) {
    int idx = blockIdx.x * 256 + threadIdx.x;
    f32x4 v = *reinterpret_cast<const f32x4*>(x + (size_t)idx * 4);
    s16x4 o;
    o[0] = f2bf(v[0]); o[1] = f2bf(v[1]); o[2] = f2bf(v[2]); o[3] = f2bf(v[3]);
    *reinterpret_cast<s16x4*>(xb + (size_t)idx * 4) = o;
}

// ---------------- wtrans ----------------
__global__ void wtrans_kernel(const float* __restrict__ W, short* __restrict__ Wt) {
    __shared__ float tile[64][65];
    int kb = blockIdx.x, nb = blockIdx.y;
    int t = threadIdx.x;
    int c4 = (t & 15) * 4;
    int r0 = t >> 4;
#pragma unroll
    for (int rr = 0; rr < 4; ++rr) {
        int kl = r0 + rr * 16;
        f32x4 v = *reinterpret_cast<const f32x4*>(W + (size_t)(kb * 64 + kl) * 3072 + nb * 64 + c4);
        tile[kl][c4 + 0] = v[0]; tile[kl][c4 + 1] = v[1];
        tile[kl][c4 + 2] = v[2]; tile[kl][c4 + 3] = v[3];
    }
    __syncthreads();
#pragma unroll
    for (int rr = 0; rr < 4; ++rr) {
        int nl = r0 + rr * 16;
        s16x4 o;
#pragma unroll
        for (int i = 0; i < 4; ++i) o[i] = f2bf(tile[c4 + i][nl]);
        *reinterpret_cast<s16x4*>(Wt + (size_t)(nb * 64 + nl) * 1024 + kb * 64 + c4) = o;
    }
}

// ---------------- qkv_gemm (m97 structure; V written transposed) ----------------
__global__ __launch_bounds__(256) void qkv_gemm_kernel(
    const short* __restrict__ xb, const short* __restrict__ Wt,
    const float* __restrict__ bias,
    short* __restrict__ Qo, short* __restrict__ Ko, short* __restrict__ Vto)
{
    __shared__ short As[128 * 64];
    __shared__ short Bs[128 * 64];
    int tid = threadIdx.x;
    int wave = tid >> 6, lane = tid & 63, g = lane >> 4, lr = lane & 15;
    int wr = wave >> 1, wc = wave & 1;
    int bm = blockIdx.x, bn = blockIdx.y;

    f32x4 acc[4][4];
#pragma unroll
    for (int a = 0; a < 4; ++a)
#pragma unroll
        for (int b = 0; b < 4; ++b) acc[a][b] = (f32x4){0.f, 0.f, 0.f, 0.f};

    for (int k0 = 0; k0 < 1024; k0 += 64) {
#pragma unroll
        for (int j = 0; j < 4; ++j) {
            int c = j * 256 + tid;
            int row = c >> 3, cc = c & 7;
            int scc = (cc ^ (row & 7)) * 8;
            gll16(xb + (size_t)(bm * 128 + row) * 1024 + k0 + scc,
                  &As[(j * 256 + wave * 64) * 8]);
            gll16(Wt + (size_t)(bn * 128 + row) * 1024 + k0 + scc,
                  &Bs[(j * 256 + wave * 64) * 8]);
        }
        __syncthreads();

        bf16x8 af[2][4], bfr[2][4];
#pragma unroll
        for (int mt = 0; mt < 4; ++mt) {
            int row = wr * 64 + mt * 16 + lr;
            af[0][mt] = *reinterpret_cast<const bf16x8*>(&As[row * 64 + (((g    ) ^ (lr & 7)) * 8)]);
            af[1][mt] = *reinterpret_cast<const bf16x8*>(&As[row * 64 + (((g + 4) ^ (lr & 7)) * 8)]);
        }
#pragma unroll
        for (int nt = 0; nt < 4; ++nt) {
            int row = wc * 64 + nt * 16 + lr;
            bfr[0][nt] = *reinterpret_cast<const bf16x8*>(&Bs[row * 64 + (((g    ) ^ (lr & 7)) * 8)]);
            bfr[1][nt] = *reinterpret_cast<const bf16x8*>(&Bs[row * 64 + (((g + 4) ^ (lr & 7)) * 8)]);
        }
#pragma unroll
        for (int mt = 0; mt < 4; ++mt)
#pragma unroll
            for (int nt = 0; nt < 4; ++nt) {
                acc[mt][nt] = __builtin_amdgcn_mfma_f32_16x16x32_bf16(af[0][mt], bfr[0][nt], acc[mt][nt], 0, 0, 0);
                acc[mt][nt] = __builtin_amdgcn_mfma_f32_16x16x32_bf16(af[1][mt], bfr[1][nt], acc[mt][nt], 0, 0, 0);
            }
        __syncthreads();
    }

#pragma unroll
    for (int nt = 0; nt < 4; ++nt) {
        int n = bn * 128 + wc * 64 + nt * 16 + lr;
        float bv = bias[n];
        int which = n >> 10;
        int h = (n >> 6) & 15;
        int dd = n & 63;
#pragma unroll
        for (int mt = 0; mt < 4; ++mt) {
            int m0 = bm * 128 + wr * 64 + mt * 16 + g * 4;
            int bb = m0 >> 11, s0 = m0 & 2047;
            if (which == 2) {
                // V: write transposed Vt[bh][64][2048]; r=0..3 -> contiguous s
                s16x4 o;
#pragma unroll
                for (int r = 0; r < 4; ++r) o[r] = f2bf(acc[mt][nt][r] + bv);
                *reinterpret_cast<s16x4*>(
                    Vto + ((size_t)(bb * 16 + h) * 64 + dd) * 2048 + s0) = o;
            } else {
                short* base = (which == 0) ? Qo : Ko;
#pragma unroll
                for (int r = 0; r < 4; ++r)
                    base[(((size_t)bb * 16 + h) * 2048 + s0 + r) * 64 + dd] =
                        f2bf(acc[mt][nt][r] + bv);
            }
        }
    }
}

// ---------------- attn ----------------
// grid 512; id = (bh&7) + 8*(qt + 16*(bh>>3)) -> XCD(id%8)==bh%8.
// 512 threads = 8 waves x 16 q-rows (qtile 128), KVBLK=64, dbuf LDS,
// two-deep bias prefetch with rotating named register sets.
__global__ __launch_bounds__(512, 4) void attn_kernel(
    const short* __restrict__ Qw, const short* __restrict__ Kw, const short* __restrict__ Vtw,
    const float* __restrict__ attnB, float* __restrict__ out)
{
    __shared__ short Ks [2][64 * 64];
    __shared__ short Vts[2][64 * 64];
    __shared__ short Ps [8][16 * 64];

    int id = blockIdx.x;
    int bh3 = id & 7;
    int qt  = (id >> 3) & 15;
    int bh  = ((id >> 7) << 3) | bh3;
    int b = bh >> 4, h = bh & 15;
    int tid = threadIdx.x;
    int wave = tid >> 6, lane = tid & 63, g = lane >> 4, lr = lane & 15;

    const short* Qb = Qw  + (size_t)bh * 2048 * 64;
    const short* Kb = Kw  + (size_t)bh * 2048 * 64;
    const short* Vb = Vtw + (size_t)bh * 64 * 2048;
    const float* Bp = attnB + (size_t)bh * 2048 * 2048;

    int qbase = qt * 128 + wave * 16;

    bf16x8 qf0, qf1;
    {
        const short* qp = Qb + (size_t)(qbase + lr) * 64 + g * 8;
        qf0 = *reinterpret_cast<const bf16x8*>(qp);
        qf1 = *reinterpret_cast<const bf16x8*>(qp + 32);
    }
    const float* brow = Bp + (size_t)(qbase + lr) * 2048 + g * 8;

    f32x4 Os[4], Ob[4];
#pragma unroll
    for (int dt = 0; dt < 4; ++dt) { Os[dt] = (f32x4){0.f,0.f,0.f,0.f}; Ob[dt] = (f32x4){0.f,0.f,0.f,0.f}; }
    float lsum = 0.f;

#define STAGE_KV(buf, ktt) do {                                                   \
    int row = tid >> 3, cc = tid & 7;                                             \
    int scc = (cc ^ (row & 7)) * 8;                                               \
    gll16(Kb + (size_t)((ktt) * 64 + row) * 64 + scc,                             \
          &Ks[buf][wave * 512]);                                                  \
    gll16(Vb + (size_t)row * 2048 + (ktt) * 64 + scc,                             \
          &Vts[buf][wave * 512]);                                                 \
} while (0)

#define LOADB(d0, d1, d2, d3, ktt) do {                                           \
    const float* bp_ = brow + (size_t)(ktt) * 64;                                 \
    d0 = *reinterpret_cast<const f32x4*>(bp_);                                    \
    d1 = *reinterpret_cast<const f32x4*>(bp_ + 4);                                \
    d2 = *reinterpret_cast<const f32x4*>(bp_ + 32);                               \
    d3 = *reinterpret_cast<const f32x4*>(bp_ + 36);                               \
} while (0)

#define COMPUTE(cur, xb0, xb1) do {                                               \
    f32x4 S[4];                                                                   \
    __builtin_amdgcn_s_setprio(1);                                                \
    _Pragma("unroll")                                                             \
    for (int nt = 0; nt < 4; ++nt) {                                              \
        int row = nt * 16 + lr;                                                   \
        bf16x8 kf0 = *reinterpret_cast<const bf16x8*>(&Ks[cur][row * 64 + (((g    ) ^ (lr & 7)) * 8)]); \
        bf16x8 kf1 = *reinterpret_cast<const bf16x8*>(&Ks[cur][row * 64 + (((g + 4) ^ (lr & 7)) * 8)]); \
        f32x4 s = (f32x4){0.f,0.f,0.f,0.f};                                       \
        s = __builtin_amdgcn_mfma_f32_16x16x32_bf16(kf0, qf0, s, 0, 0, 0);        \
        s = __builtin_amdgcn_mfma_f32_16x16x32_bf16(kf1, qf1, s, 0, 0, 0);        \
        S[nt] = s;                                                                \
    }                                                                             \
    __builtin_amdgcn_s_setprio(0);                                                \
    _Pragma("unroll")                                                             \
    for (int nt = 0; nt < 4; ++nt)                                                \
        _Pragma("unroll")                                                         \
        for (int r = 0; r < 4; ++r) {                                             \
            float p = exp2f(S[nt][r] * 0.1803368801111f);                         \
            S[nt][r] = p;                                                         \
            lsum += p;                                                            \
        }                                                                         \
    short* psw = &Ps[wave][lr * 64];                                              \
    _Pragma("unroll")                                                             \
    for (int nt = 0; nt < 4; ++nt)                                                \
        _Pragma("unroll")                                                         \
        for (int rp = 0; rp < 2; ++rp) {                                          \
            unsigned w = cvt_pk_bf16(S[nt][2 * rp], S[nt][2 * rp + 1]);           \
            int kp = 8 * nt + 2 * g + rp;                                         \
            int bi = kp >> 2, off = kp & 3;                                       \
            *reinterpret_cast<unsigned*>(psw + ((bi ^ (lr & 7)) << 3) + off * 2) = w; \
        }                                                                         \
    bf16x8 pf0 = *reinterpret_cast<const bf16x8*>(&Ps[wave][lr * 64 + (((g    ) ^ (lr & 7)) * 8)]); \
    bf16x8 pf1 = *reinterpret_cast<const bf16x8*>(&Ps[wave][lr * 64 + (((g + 4) ^ (lr & 7)) * 8)]); \
    __builtin_amdgcn_s_setprio(1);                                                \
    _Pragma("unroll")                                                             \
    for (int dt = 0; dt < 4; ++dt) {                                              \
        int row = dt * 16 + lr;                                                   \
        bf16x8 v0 = *reinterpret_cast<const bf16x8*>(&Vts[cur][row * 64 + (((g    ) ^ (lr & 7)) * 8)]); \
        bf16x8 v1 = *reinterpret_cast<const bf16x8*>(&Vts[cur][row * 64 + (((g + 4) ^ (lr & 7)) * 8)]); \
        Os[dt] = __builtin_amdgcn_mfma_f32_16x16x32_bf16(pf0, v0, Os[dt], 0, 0, 0); \
        Os[dt] = __builtin_amdgcn_mfma_f32_16x16x32_bf16(pf1, v1, Os[dt], 0, 0, 0); \
        Ob[dt] = __builtin_amdgcn_mfma_f32_16x16x32_bf16(xb0, v0, Ob[dt], 0, 0, 0); \
        Ob[dt] = __builtin_amdgcn_mfma_f32_16x16x32_bf16(xb1, v1, Ob[dt], 0, 0, 0); \
    }                                                                             \
    __builtin_amdgcn_s_setprio(0);                                                \
} while (0)

    // bias register sets: A holds even tiles, B holds odd tiles
    f32x4 a0, a1, a2, a3, p0, p1, p2, p3;

    // prologue: stage tile 0 (FIRST, for vmcnt FIFO), then bias 0 and 1
    STAGE_KV(0, 0);
    __builtin_amdgcn_sched_barrier(0);
    LOADB(a0, a1, a2, a3, 0);
    LOADB(p0, p1, p2, p3, 1);
    __builtin_amdgcn_sched_barrier(0);
    asm volatile("s_waitcnt vmcnt(8)" ::: "memory");   // stage(0) done; 8 bias in flight
    __builtin_amdgcn_s_barrier();
    __builtin_amdgcn_sched_barrier(0);

    for (int t = 0; t < 16; ++t) {
        // ======== even iter kt = 2t, tile in buf0 ========
        {
            bf16x8 bbf0 = pack8(a0, a1);
            bf16x8 bbf1 = pack8(a2, a3);
            STAGE_KV(1, 2 * t + 1);                    // stage FIRST (FIFO)
            __builtin_amdgcn_sched_barrier(0);
            if (t < 15) LOADB(a0, a1, a2, a3, 2 * t + 2);
            __builtin_amdgcn_sched_barrier(0);
            COMPUTE(0, bbf0, bbf1);
            if (t < 15) {
                asm volatile("s_waitcnt vmcnt(4)" ::: "memory");  // bias(2t+1)+stage done
            } else {
                asm volatile("s_waitcnt vmcnt(0)" ::: "memory");  // tail: drain all
            }
            __builtin_amdgcn_s_barrier();
            __builtin_amdgcn_sched_barrier(0);
        }
        // ======== odd iter kt = 2t+1, tile in buf1 ========
        {
            bf16x8 bbf0 = pack8(p0, p1);
            bf16x8 bbf1 = pack8(p2, p3);
            if (t < 15) {
                STAGE_KV(0, 2 * t + 2);
                __builtin_amdgcn_sched_barrier(0);
                LOADB(p0, p1, p2, p3, 2 * t + 3);
                __builtin_amdgcn_sched_barrier(0);
            }
            COMPUTE(1, bbf0, bbf1);
            if (t < 15) {
                asm volatile("s_waitcnt vmcnt(4)" ::: "memory");  // bias(2t+2)+stage done
                __builtin_amdgcn_s_barrier();
                __builtin_amdgcn_sched_barrier(0);
            }
        }
    }
#undef STAGE_KV
#undef LOADB
#undef COMPUTE

    // ---- epilogue: reduce row sums across the 4 lane-groups ----
    float l = lsum;
    l += __shfl_xor(l, 16);
    l += __shfl_xor(l, 32);
    float inv = 1.0f / l;          // lane holds inv for q = lr
#pragma unroll
    for (int r = 0; r < 4; ++r) {
        float invr = __shfl(inv, g * 4 + r);   // inv for q = 4g + r
        int q = qbase + g * 4 + r;
#pragma unroll
        for (int dt = 0; dt < 4; ++dt) {
            int dcol = dt * 16 + lr;
            float v = Os[dt][r] * invr + Ob[dt][r];
            __builtin_nontemporal_store(v, &out[((size_t)(b * 2048 + q) * 16 + h) * 64 + dcol]);
        }
    }
}

extern "C" void kernel_launch(void* const* d_in, const int* in_sizes, int n_in,
                              void* d_out, int out_size, void* d_ws, size_t ws_size,
                              hipStream_t stream) {
    const float* x     = (const float*)d_in[0];
    const float* attnB = (const float*)d_in[1];
    const float* W     = (const float*)d_in[2];
    const float* bias  = (const float*)d_in[3];
    float* out = (float*)d_out;

    short* ws = (short*)d_ws;
    short* xb = ws;                // 4,194,304 shorts
    short* Wt = xb + 4194304;      // 3,145,728
    short* Q  = Wt + 3145728;      // 4,194,304
    short* K  = Q  + 4194304;      // 4,194,304
    short* Vt = K  + 4194304;      // 4,194,304

    conv_x_kernel<<<4096, 256, 0, stream>>>(x, xb);
    wtrans_kernel<<<dim3(16, 48), 256, 0, stream>>>(W, Wt);
    qkv_gemm_kernel<<<dim3(32, 24), 256, 0, stream>>>(xb, Wt, bias, Q, K, Vt);
    attn_kernel<<<512, 512, 0, stream>>>(Q, K, Vt, attnB, out);
}